// Round 10
// baseline (43.376 us; speedup 1.0000x reference)
//
#include <hip/hip_runtime.h>
#include <hip/hip_fp16.h>

#define NR 700
#define KK 250
#define HID 32

typedef unsigned int uint32;
typedef _Float16 hpair __attribute__((ext_vector_type(2)));

#if __has_builtin(__builtin_amdgcn_fdot2)
#define FDOT2(a, b, c) __builtin_amdgcn_fdot2((a), (b), (c), false)
#else
#define FDOT2(a, b, c) fmaf((float)(a).x, (float)(b).x, fmaf((float)(a).y, (float)(b).y, (c)))
#endif

__device__ __forceinline__ hpair u2p(uint32 u) { return __builtin_bit_cast(hpair, u); }
__device__ __forceinline__ uint32 packh2(float lo, float hi) {
    hpair p; p.x = (_Float16)lo; p.y = (_Float16)hi;
    return __builtin_bit_cast(uint32, p);
}

// Full-rate fp32 exp2: magic-RNE split + deg-3 poly + exponent splice.
// 9 full-rate VALU ops, no transcendental, no clamp (valid for |s| < ~126).
__device__ __forceinline__ float exp2_fast(float s) {
    const float MAGF = 12582912.0f;            // 1.5 * 2^23
    float y  = s + MAGF;                       // bits(y) = 0x4B400000 + n
    float nf = y - MAGF;                       // n = rne(s)
    float f  = s - nf;                         // f in [-0.5, 0.5]
    float p  = fmaf(f, fmaf(f, fmaf(f, 0.055504110f, 0.240226507f),
                             0.693147181f), 1.0f);
    int e = (__builtin_bit_cast(int, y) + 127) << 23;   // bits of 2^n
    return p * __builtin_bit_cast(float, e);
}

__device__ __forceinline__ void compute_weights(
    int wt, int l,
    const float* __restrict__ Wq, const float* __restrict__ bq,
    const float* __restrict__ Wk,
    const float* __restrict__ Wv, const float* __restrict__ bv,
    float (*Msh)[7], float* wsh, float* wvsh, float SC2)
{
    const float* wq = Wq + l * 7 * HID;
    const float* wk = Wk + l * 7 * HID;
    if (wt < 49) {
        int c = wt / 7, cp = wt % 7;
        float s = 0.f;
        #pragma unroll 8
        for (int d = 0; d < HID; ++d) s = fmaf(wq[c * HID + d], wk[cp * HID + d], s);
        Msh[c][cp] = s * SC2;
    } else if (wt < 56) {
        int cp = wt - 49;
        float s = 0.f;
        #pragma unroll 8
        for (int d = 0; d < HID; ++d) s = fmaf(bq[l * HID + d], wk[cp * HID + d], s);
        wsh[cp] = s * SC2;
    } else if (wt < 63) {
        wvsh[wt - 56] = Wv[l * 7 + (wt - 56)];
    } else if (wt == 63) {
        wvsh[7] = bv[l];
    }
}

// 512 threads = 8 waves. Lane-quad owns 2 query rows: row0 = tid>>2, row1 = row0+128;
// jq = tid&3 picks a j-quarter. One ds_read_b128 per iter serves 2 rows; v lives in
// the h-row's 8th fp16 slot (nulled in the score by t*d.y = 0). Quad-reduce = 2 shfl_xor.
__global__ __launch_bounds__(512, 4) void mlra_kernel(
    const float* __restrict__ power,
    const int*   __restrict__ ele_idx,
    const int*   __restrict__ azi_idx,
    const float* __restrict__ ele_emb,
    const float* __restrict__ azi_emb,
    const float* __restrict__ Wq,
    const float* __restrict__ bq,
    const float* __restrict__ Wk,
    const float* __restrict__ bk,
    const float* __restrict__ Wv,
    const float* __restrict__ bv,
    float* __restrict__ out)
{
    __shared__ uint4 hh[256];        // 8 fp16/row: (h0,h1)(h2,h3)(h4,h5)(h6,v); pads zero
    __shared__ float Msh[2][7][7];   // both layers' folded SC2*Wq Wk^T
    __shared__ float wsh[2][7];
    __shared__ float wvsh[2][8];

    uint32* hhU = reinterpret_cast<uint32*>(hh);

    const int r    = blockIdx.x;
    const int tid  = threadIdx.x;
    const int row0 = tid >> 2;        // 0..127
    const int row1 = row0 + 128;      // 128..255
    const int jq   = tid & 3;

    const float SC2 = 0.17677669529663687f * 1.4426950408889634f;

    // ---- prologue: h build (threads 0-255) || both layers' weights (waves 4,5) ----
    if (tid < 256) {
        float hv[8];
        if (tid < KK) {
            int g = r * KK + tid;
            hv[0] = power[g];
            int ei = ele_idx[g];
            int ai = azi_idx[g];
            hv[1] = ele_emb[ei * 3 + 0];
            hv[2] = ele_emb[ei * 3 + 1];
            hv[3] = ele_emb[ei * 3 + 2];
            hv[4] = azi_emb[ai * 3 + 0];
            hv[5] = azi_emb[ai * 3 + 1];
            hv[6] = azi_emb[ai * 3 + 2];
            hv[7] = 0.f;
        } else {
            #pragma unroll
            for (int c = 0; c < 8; ++c) hv[c] = 0.f;
        }
        uint4 u;
        u.x = packh2(hv[0], hv[1]);
        u.y = packh2(hv[2], hv[3]);
        u.z = packh2(hv[4], hv[5]);
        u.w = packh2(hv[6], 0.f);    // v filled per layer in t-phase
        hh[tid] = u;
    } else if (tid < 384) {
        int l = (tid - 256) >> 6;    // wave 4 -> layer 0, wave 5 -> layer 1
        compute_weights(tid & 63, l, Wq, bq, Wk, Wv, bv, Msh[l], wsh[l], wvsh[l], SC2);
    }
    __syncthreads();   // (1) h + both layers' weights ready

    float x0 = 0.f, x1 = 0.f;

    for (int l = 0; l < 2; ++l) {
        // ---- t-phase: unpack 2 fp16 rows, build t vectors; jq==0 computes v ----
        uint4 u0 = hh[row0];
        uint4 u1 = hh[row1];
        hpair a0 = u2p(u0.x), b0 = u2p(u0.y), c0 = u2p(u0.z), d0 = u2p(u0.w);
        hpair a1 = u2p(u1.x), b1 = u2p(u1.y), c1 = u2p(u1.z), d1 = u2p(u1.w);
        float hv0[7] = {(float)a0.x, (float)a0.y, (float)b0.x, (float)b0.y,
                        (float)c0.x, (float)c0.y, (float)d0.x};
        float hv1[7] = {(float)a1.x, (float)a1.y, (float)b1.x, (float)b1.y,
                        (float)c1.x, (float)c1.y, (float)d1.x};
        float tt0[7], tt1[7];
        #pragma unroll
        for (int cp = 0; cp < 7; ++cp) {
            float s0 = wsh[l][cp], s1 = wsh[l][cp];
            #pragma unroll
            for (int c = 0; c < 7; ++c) {
                float m = Msh[l][c][cp];
                s0 = fmaf(hv0[c], m, s0);
                s1 = fmaf(hv1[c], m, s1);
            }
            tt0[cp] = s0; tt1[cp] = s1;
        }
        hpair t0a = u2p(packh2(tt0[0], tt0[1]));
        hpair t0b = u2p(packh2(tt0[2], tt0[3]));
        hpair t0c = u2p(packh2(tt0[4], tt0[5]));
        hpair t0d = u2p(packh2(tt0[6], 0.f));   // .y = 0 nullifies the v slot
        hpair t1a = u2p(packh2(tt1[0], tt1[1]));
        hpair t1b = u2p(packh2(tt1[2], tt1[3]));
        hpair t1c = u2p(packh2(tt1[4], tt1[5]));
        hpair t1d = u2p(packh2(tt1[6], 0.f));
        if (jq == 0) {
            float v0 = wvsh[l][7], v1 = wvsh[l][7];
            #pragma unroll
            for (int c = 0; c < 7; ++c) {
                v0 = fmaf(hv0[c], wvsh[l][c], v0);
                v1 = fmaf(hv1[c], wvsh[l][c], v1);
            }
            hhU[row0 * 4 + 3] = packh2(hv0[6], v0);            // row0 < KK always
            if (row1 < KK) hhU[row1 * 4 + 3] = packh2(hv1[6], v1);
        }
        __syncthreads();   // (2) v ready

        // ---- inner: 64 iters over this quad's j-quarter, 2 rows per iter ----
        float ss0 = 0.f, oo0 = 0.f, ss1 = 0.f, oo1 = 0.f;
        #pragma unroll 8
        for (int it = 0; it < 64; ++it) {
            const int j = (it << 2) | jq;
            uint4 ua = hh[j];            // 4 distinct addrs/wave
            float vj = (float)u2p(ua.w).y;
            float sc0 = FDOT2(u2p(ua.x), t0a,
                        FDOT2(u2p(ua.y), t0b,
                        FDOT2(u2p(ua.z), t0c,
                        FDOT2(u2p(ua.w), t0d, 0.f))));
            float sc1 = FDOT2(u2p(ua.x), t1a,
                        FDOT2(u2p(ua.y), t1b,
                        FDOT2(u2p(ua.z), t1c,
                        FDOT2(u2p(ua.w), t1d, 0.f))));
            float p0 = exp2_fast(sc0);
            float p1 = exp2_fast(sc1);
            ss0 += p0; oo0 = fmaf(p0, vj, oo0);
            ss1 += p1; oo1 = fmaf(p1, vj, oo1);
        }
        // pad rows 250..255 (zeroed): jq 0,1 visit 1 pad; jq 2,3 visit 2 (p=1, v=0)
        const float corr = 1.0f + (float)(jq >> 1);
        ss0 -= corr; ss1 -= corr;

        // ---- quad reduce (xor 1, then 2) ----
        ss0 += __shfl_xor(ss0, 1); ss0 += __shfl_xor(ss0, 2);
        oo0 += __shfl_xor(oo0, 1); oo0 += __shfl_xor(oo0, 2);
        ss1 += __shfl_xor(ss1, 1); ss1 += __shfl_xor(ss1, 2);
        oo1 += __shfl_xor(oo1, 1); oo1 += __shfl_xor(oo1, 2);
        x0 = oo0 / ss0;
        x1 = oo1 / ss1;

        if (l == 0) {
            __syncthreads();   // (3) all inner reads of hh done
            if (jq == 0) {
                hhU[row0 * 4 + 0] = packh2(x0, hv0[1]);        // layer-1 input (fp16)
                if (row1 < KK) hhU[row1 * 4 + 0] = packh2(x1, hv1[1]);
            }
            __syncthreads();   // (4) x-update published
        }
    }

    if (jq == 0) {
        out[r * KK + row0] = x0;
        if (row1 < KK) out[r * KK + row1] = x1;
    }
}

extern "C" void kernel_launch(void* const* d_in, const int* in_sizes, int n_in,
                              void* d_out, int out_size, void* d_ws, size_t ws_size,
                              hipStream_t stream) {
    const float* power   = (const float*)d_in[0];
    const int*   ele     = (const int*)d_in[1];
    const int*   azi     = (const int*)d_in[2];
    const float* ele_emb = (const float*)d_in[3];
    const float* azi_emb = (const float*)d_in[4];
    const float* Wq      = (const float*)d_in[5];
    const float* bq      = (const float*)d_in[6];
    const float* Wk      = (const float*)d_in[7];
    const float* bk      = (const float*)d_in[8];
    const float* Wv      = (const float*)d_in[9];
    const float* bv      = (const float*)d_in[10];
    float* outp = (float*)d_out;
    (void)bk;

    hipLaunchKernelGGL(mlra_kernel, dim3(NR), dim3(512), 0, stream,
                       power, ele, azi, ele_emb, azi_emb, Wq, bq, Wk, bk, Wv, bv, outp);
}